// Round 1
// baseline (580.158 us; speedup 1.0000x reference)
//
#include <hip/hip_runtime.h>
#include <hip/hip_bf16.h>
#include <stdint.h>

#define M_DIM 8192
#define K_DIM 4096
#define N_DIM 4096
#define QO 1024
#define BM 128
#define BN 128
#define BK 32

typedef __bf16 bf16x8_t __attribute__((ext_vector_type(8)));
typedef float f32x4_t __attribute__((ext_vector_type(4)));

__device__ __forceinline__ uint32_t f2bf_rne(float f) {
    union { float f; uint32_t u; } v; v.f = f;
    return (v.u + 0x7FFFu + ((v.u >> 16) & 1u)) >> 16;
}
__device__ __forceinline__ uint32_t pack2bf(float lo, float hi) {
    return f2bf_rne(lo) | (f2bf_rne(hi) << 16);
}

// ---- prep 1: X fp32 -> bf16 -------------------------------------------------
__global__ __launch_bounds__(256) void cvt_x_kernel(const float* __restrict__ x,
                                                    uint16_t* __restrict__ xb, int n4) {
    int i = blockIdx.x * 256 + threadIdx.x;
    if (i >= n4) return;
    float4 v = ((const float4*)x)[i];
    uint2 o;
    o.x = pack2bf(v.x, v.y);
    o.y = pack2bf(v.z, v.w);
    ((uint2*)xb)[i] = o;
}

// ---- prep 2: build W_big (4096 x 4096, N-major rows = output features) ------
// block (c'=n>>10, c=k>>10): type = c'^c (0=rr,1=ri,2=rj,3=rk)
// neg entries at flat index c'*4+c in {1,2,3,7,9,14} -> mask 0x428E
__global__ __launch_bounds__(256) void build_w_kernel(
    const float* __restrict__ wrr, const float* __restrict__ wri,
    const float* __restrict__ wrj, const float* __restrict__ wrk,
    uint16_t* __restrict__ wb, int n4) {
    int g = blockIdx.x * 256 + threadIdx.x;
    if (g >= n4) return;
    int n  = g >> 10;
    int k4 = (g & 1023) << 2;
    int cp = n >> 10, o = n & 1023;
    int c  = k4 >> 10, i = k4 & 1023;
    int tsel = cp ^ c;
    const float* w = (tsel == 0) ? wrr : (tsel == 1) ? wri : (tsel == 2) ? wrj : wrk;
    float s = ((0x428Eu >> ((cp << 2) | c)) & 1u) ? -1.0f : 1.0f;
    float4 v = *(const float4*)(w + (size_t)o * QO + i);
    uint2 ob;
    ob.x = pack2bf(s * v.x, s * v.y);
    ob.y = pack2bf(s * v.z, s * v.w);
    ((uint2*)wb)[g] = ob;
}

// ---- GEMM: C[M,N] = A[M,K] * B[N,K]^T + bias, m97-style ---------------------
template <bool USE_WS>
__global__ __launch_bounds__(256) void qgemm_kernel(
    const uint16_t* __restrict__ Abf, const uint16_t* __restrict__ Bbf,
    const float* __restrict__ x,
    const float* __restrict__ wrr, const float* __restrict__ wri,
    const float* __restrict__ wrj, const float* __restrict__ wrk,
    const float* __restrict__ bias, float* __restrict__ C)
{
    __shared__ uint16_t lA[BM * BK];   // [row][32] unpadded: required by global_load_lds
    __shared__ uint16_t lB[BN * BK];
    const int t    = threadIdx.x;
    const int wave = t >> 6;
    const int lane = t & 63;
    const int bn = blockIdx.x, bm = blockIdx.y;
    const int wm = wave >> 1, wn = wave & 1;

    f32x4_t acc[4][4];
#pragma unroll
    for (int a = 0; a < 4; ++a)
#pragma unroll
        for (int b = 0; b < 4; ++b)
            acc[a][b] = (f32x4_t){0.f, 0.f, 0.f, 0.f};

    // loop-invariant LDS fragment addresses (A-op: row=lane&15, k=8*(lane>>4)+j; B symmetric)
    const int fr  = lane & 15;
    const int fkb = (lane >> 4) << 3;
    const uint16_t* pA[4];
    const uint16_t* pB[4];
#pragma unroll
    for (int i = 0; i < 4; ++i) {
        pA[i] = lA + (wm * 64 + i * 16 + fr) * BK + fkb;
        pB[i] = lB + (wn * 64 + i * 16 + fr) * BK + fkb;
    }

    // fast-path staging: wave w covers rows 16w..16w+15 (and +64), lane l -> row 16w+l/4, col (l%4)*8
    const int srow = lane >> 2;
    const int scol = (lane & 3) << 3;
    const uint16_t* gA0 = nullptr;
    const uint16_t* gB0 = nullptr;
    uint16_t* lA0 = nullptr;
    uint16_t* lB0 = nullptr;
    if constexpr (USE_WS) {
        gA0 = Abf + (size_t)(bm * BM + wave * 16 + srow) * K_DIM + scol;
        gB0 = Bbf + (size_t)(bn * BN + wave * 16 + srow) * K_DIM + scol;
        lA0 = lA + wave * 16 * BK;
        lB0 = lB + wave * 16 * BK;
    }
    // fallback staging: thread t -> tile row t/2, 16 cols at (t&1)*16
    const int mr = t >> 1;
    const int mc = (t & 1) << 4;
    int bcp = 0, bo = 0;
    if constexpr (!USE_WS) {
        int ng = bn * BN + mr;
        bcp = ng >> 10;
        bo  = ng & 1023;
    }

#pragma unroll 1
    for (int kb = 0; kb < K_DIM; kb += BK) {
        if constexpr (USE_WS) {
            __builtin_amdgcn_global_load_lds(
                (const __attribute__((address_space(1))) void*)(gA0 + kb),
                (__attribute__((address_space(3))) void*)lA0, 16, 0, 0);
            __builtin_amdgcn_global_load_lds(
                (const __attribute__((address_space(1))) void*)(gA0 + (size_t)64 * K_DIM + kb),
                (__attribute__((address_space(3))) void*)(lA0 + 64 * BK), 16, 0, 0);
            __builtin_amdgcn_global_load_lds(
                (const __attribute__((address_space(1))) void*)(gB0 + kb),
                (__attribute__((address_space(3))) void*)lB0, 16, 0, 0);
            __builtin_amdgcn_global_load_lds(
                (const __attribute__((address_space(1))) void*)(gB0 + (size_t)64 * K_DIM + kb),
                (__attribute__((address_space(3))) void*)(lB0 + 64 * BK), 16, 0, 0);
        } else {
            const float* pa = x + (size_t)(bm * BM + mr) * K_DIM + kb + mc;
            float4 a0 = ((const float4*)pa)[0], a1 = ((const float4*)pa)[1],
                   a2 = ((const float4*)pa)[2], a3 = ((const float4*)pa)[3];
            uint4 wv0 = make_uint4(pack2bf(a0.x, a0.y), pack2bf(a0.z, a0.w),
                                   pack2bf(a1.x, a1.y), pack2bf(a1.z, a1.w));
            uint4 wv1 = make_uint4(pack2bf(a2.x, a2.y), pack2bf(a2.z, a2.w),
                                   pack2bf(a3.x, a3.y), pack2bf(a3.z, a3.w));
            *(uint4*)(lA + mr * BK + mc)     = wv0;
            *(uint4*)(lA + mr * BK + mc + 8) = wv1;

            int k0 = kb + mc;
            int c  = k0 >> 10, ii = k0 & 1023;
            int tsel = bcp ^ c;
            const float* w = (tsel == 0) ? wrr : (tsel == 1) ? wri : (tsel == 2) ? wrj : wrk;
            float s = ((0x428Eu >> ((bcp << 2) | c)) & 1u) ? -1.0f : 1.0f;
            const float* pb = w + (size_t)bo * QO + ii;
            float4 b0 = ((const float4*)pb)[0], b1 = ((const float4*)pb)[1],
                   b2 = ((const float4*)pb)[2], b3 = ((const float4*)pb)[3];
            uint4 u0 = make_uint4(pack2bf(s * b0.x, s * b0.y), pack2bf(s * b0.z, s * b0.w),
                                  pack2bf(s * b1.x, s * b1.y), pack2bf(s * b1.z, s * b1.w));
            uint4 u1 = make_uint4(pack2bf(s * b2.x, s * b2.y), pack2bf(s * b2.z, s * b2.w),
                                  pack2bf(s * b3.x, s * b3.y), pack2bf(s * b3.z, s * b3.w));
            *(uint4*)(lB + mr * BK + mc)     = u0;
            *(uint4*)(lB + mr * BK + mc + 8) = u1;
        }
        __syncthreads();

        bf16x8_t af[4], bfr[4];
#pragma unroll
        for (int i = 0; i < 4; ++i) {
            af[i]  = *(const bf16x8_t*)pA[i];
            bfr[i] = *(const bf16x8_t*)pB[i];
        }
#pragma unroll
        for (int mi = 0; mi < 4; ++mi)
#pragma unroll
            for (int ni = 0; ni < 4; ++ni)
                acc[mi][ni] = __builtin_amdgcn_mfma_f32_16x16x32_bf16(
                    af[mi], bfr[ni], acc[mi][ni], 0, 0, 0);
        __syncthreads();
    }

    // epilogue: C/D layout col=lane&15, row=(lane>>4)*4+reg (verified mapping)
    const int row0 = bm * BM + wm * 64 + ((lane >> 4) << 2);
    const int col0 = bn * BN + wn * 64 + (lane & 15);
#pragma unroll
    for (int ni = 0; ni < 4; ++ni) {
        const int col = col0 + ni * 16;
        const float bv = bias[col & (QO - 1)];
#pragma unroll
        for (int mi = 0; mi < 4; ++mi) {
            const int r = row0 + mi * 16;
            float* cptr = C + (size_t)r * N_DIM + col;
#pragma unroll
            for (int rr = 0; rr < 4; ++rr)
                cptr[(size_t)rr * N_DIM] = acc[mi][ni][rr] + bv;
        }
    }
}

extern "C" void kernel_launch(void* const* d_in, const int* in_sizes, int n_in,
                              void* d_out, int out_size, void* d_ws, size_t ws_size,
                              hipStream_t stream) {
    const float* x   = (const float*)d_in[0];
    const float* wrr = (const float*)d_in[1];
    const float* wri = (const float*)d_in[2];
    const float* wrj = (const float*)d_in[3];
    const float* wrk = (const float*)d_in[4];
    const float* brr = (const float*)d_in[5];
    float* out = (float*)d_out;

    const size_t xb_bytes = (size_t)M_DIM * K_DIM * 2;   // 64 MiB
    const size_t wb_bytes = (size_t)N_DIM * K_DIM * 2;   // 32 MiB
    dim3 grid(N_DIM / BN, M_DIM / BM);

    if (ws_size >= xb_bytes + wb_bytes) {
        uint16_t* xb = (uint16_t*)d_ws;
        uint16_t* wb = (uint16_t*)((char*)d_ws + xb_bytes);
        const int nx4 = M_DIM * K_DIM / 4;
        cvt_x_kernel<<<nx4 / 256, 256, 0, stream>>>(x, xb, nx4);
        const int nw4 = N_DIM * K_DIM / 4;
        build_w_kernel<<<nw4 / 256, 256, 0, stream>>>(wrr, wri, wrj, wrk, wb, nw4);
        qgemm_kernel<true><<<grid, 256, 0, stream>>>(xb, wb, x, wrr, wri, wrj, wrk, brr, out);
    } else {
        qgemm_kernel<false><<<grid, 256, 0, stream>>>(nullptr, nullptr, x, wrr, wri, wrj, wrk, brr, out);
    }
}

// Round 2
// 550.028 us; speedup vs baseline: 1.0548x; 1.0548x over previous
//
#include <hip/hip_runtime.h>
#include <hip/hip_bf16.h>
#include <stdint.h>

#define M_DIM 8192
#define K_DIM 4096
#define N_DIM 4096
#define QO 1024
// fast-path GEMM tile
#define BM 256
#define BN 128
#define BK 32
// fallback tile
#define FBM 128
#define FBN 128

typedef __bf16 bf16x8_t __attribute__((ext_vector_type(8)));
typedef float f32x4_t __attribute__((ext_vector_type(4)));

__device__ __forceinline__ uint32_t f2bf_rne(float f) {
    union { float f; uint32_t u; } v; v.f = f;
    return (v.u + 0x7FFFu + ((v.u >> 16) & 1u)) >> 16;
}
__device__ __forceinline__ uint32_t pack2bf(float lo, float hi) {
    return f2bf_rne(lo) | (f2bf_rne(hi) << 16);
}

// ---- prep 1: X fp32 -> bf16 (8 floats/thread, 16B store) --------------------
__global__ __launch_bounds__(256) void cvt_x_kernel(const float* __restrict__ x,
                                                    uint16_t* __restrict__ xb, int n8) {
    int i = blockIdx.x * 256 + threadIdx.x;
    if (i >= n8) return;
    float4 v0 = ((const float4*)x)[2 * i];
    float4 v1 = ((const float4*)x)[2 * i + 1];
    uint4 o;
    o.x = pack2bf(v0.x, v0.y);
    o.y = pack2bf(v0.z, v0.w);
    o.z = pack2bf(v1.x, v1.y);
    o.w = pack2bf(v1.z, v1.w);
    ((uint4*)xb)[i] = o;
}

// ---- prep 2: build W_big (4096 x 4096, N-major rows = output features) ------
// block (c'=n>>10, c=k>>10): type = c'^c (0=rr,1=ri,2=rj,3=rk)
// neg entries at flat index c'*4+c in {1,2,3,7,9,14} -> mask 0x428E
__global__ __launch_bounds__(256) void build_w_kernel(
    const float* __restrict__ wrr, const float* __restrict__ wri,
    const float* __restrict__ wrj, const float* __restrict__ wrk,
    uint16_t* __restrict__ wb, int n8) {
    int g = blockIdx.x * 256 + threadIdx.x;
    if (g >= n8) return;
    int n  = g >> 9;                 // 512 groups of 8 per output row
    int k8 = (g & 511) << 3;
    int cp = n >> 10, o = n & 1023;
    int c  = k8 >> 10, i = k8 & 1023;
    int tsel = cp ^ c;
    const float* w = (tsel == 0) ? wrr : (tsel == 1) ? wri : (tsel == 2) ? wrj : wrk;
    float s = ((0x428Eu >> ((cp << 2) | c)) & 1u) ? -1.0f : 1.0f;
    const float* p = w + (size_t)o * QO + i;
    float4 v0 = ((const float4*)p)[0];
    float4 v1 = ((const float4*)p)[1];
    uint4 ob;
    ob.x = pack2bf(s * v0.x, s * v0.y);
    ob.y = pack2bf(s * v0.z, s * v0.w);
    ob.z = pack2bf(s * v1.x, s * v1.y);
    ob.w = pack2bf(s * v1.z, s * v1.w);
    ((uint4*)wb)[g] = ob;
}

// ---- fast GEMM: 256x128 block, 128x64 wave tile, 8x4 acc --------------------
__global__ __launch_bounds__(256, 2) void qgemm256_kernel(
    const uint16_t* __restrict__ Abf, const uint16_t* __restrict__ Bbf,
    const float* __restrict__ bias, float* __restrict__ C)
{
    __shared__ uint16_t lA[BM * BK];   // [row][32] unpadded: required by global_load_lds
    __shared__ uint16_t lB[BN * BK];
    const int t    = threadIdx.x;
    const int wave = t >> 6;
    const int lane = t & 63;
    const int bn = blockIdx.x, bm = blockIdx.y;
    const int wm = wave >> 1, wn = wave & 1;   // 2x2 waves, wave tile 128x64

    f32x4_t acc[8][4];
#pragma unroll
    for (int a = 0; a < 8; ++a)
#pragma unroll
        for (int b = 0; b < 4; ++b)
            acc[a][b] = (f32x4_t){0.f, 0.f, 0.f, 0.f};

    // fragment LDS addresses (A-op: row=lane&15, k=8*(lane>>4)+j; B symmetric)
    const int fr  = lane & 15;
    const int fkb = (lane >> 4) << 3;
    const uint16_t* pA[8];
    const uint16_t* pB[4];
#pragma unroll
    for (int i = 0; i < 8; ++i)
        pA[i] = lA + (wm * 128 + i * 16 + fr) * BK + fkb;
#pragma unroll
    for (int i = 0; i < 4; ++i)
        pB[i] = lB + (wn * 64 + i * 16 + fr) * BK + fkb;

    // staging: lane l -> row l/4, col (l%4)*8 within each 16-row group (1024 B)
    const int srow = lane >> 2;
    const int scol = (lane & 3) << 3;
    const uint16_t* gA0 = Abf + (size_t)(bm * BM + wave * 64 + srow) * K_DIM + scol;
    const uint16_t* gB0 = Bbf + (size_t)(bn * BN + wave * 32 + srow) * K_DIM + scol;
    uint16_t* lA0 = lA + wave * 64 * BK;
    uint16_t* lB0 = lB + wave * 32 * BK;

#pragma unroll 1
    for (int kb = 0; kb < K_DIM; kb += BK) {
#pragma unroll
        for (int i = 0; i < 4; ++i)
            __builtin_amdgcn_global_load_lds(
                (const __attribute__((address_space(1))) void*)(gA0 + (size_t)i * 16 * K_DIM + kb),
                (__attribute__((address_space(3))) void*)(lA0 + i * 16 * BK), 16, 0, 0);
#pragma unroll
        for (int i = 0; i < 2; ++i)
            __builtin_amdgcn_global_load_lds(
                (const __attribute__((address_space(1))) void*)(gB0 + (size_t)i * 16 * K_DIM + kb),
                (__attribute__((address_space(3))) void*)(lB0 + i * 16 * BK), 16, 0, 0);
        __syncthreads();

        bf16x8_t bfr[4];
#pragma unroll
        for (int i = 0; i < 4; ++i)
            bfr[i] = *(const bf16x8_t*)pB[i];
#pragma unroll
        for (int mi = 0; mi < 8; ++mi) {
            bf16x8_t af = *(const bf16x8_t*)pA[mi];
#pragma unroll
            for (int ni = 0; ni < 4; ++ni)
                acc[mi][ni] = __builtin_amdgcn_mfma_f32_16x16x32_bf16(
                    af, bfr[ni], acc[mi][ni], 0, 0, 0);
        }
        __syncthreads();
    }

    // epilogue: C/D layout col=lane&15, row=(lane>>4)*4+reg
    const int row0 = bm * BM + wm * 128 + ((lane >> 4) << 2);
    const int col0 = bn * BN + wn * 64 + (lane & 15);
#pragma unroll
    for (int ni = 0; ni < 4; ++ni) {
        const int col = col0 + ni * 16;
        const float bv = bias[col & (QO - 1)];
#pragma unroll
        for (int mi = 0; mi < 8; ++mi) {
            const int r = row0 + mi * 16;
            float* cptr = C + (size_t)r * N_DIM + col;
#pragma unroll
            for (int rr = 0; rr < 4; ++rr)
                cptr[(size_t)rr * N_DIM] = acc[mi][ni][rr] + bv;
        }
    }
}

// ---- fallback GEMM (no ws): fp32 inputs, on-the-fly bf16 convert ------------
__global__ __launch_bounds__(256) void qgemm_fb_kernel(
    const float* __restrict__ x,
    const float* __restrict__ wrr, const float* __restrict__ wri,
    const float* __restrict__ wrj, const float* __restrict__ wrk,
    const float* __restrict__ bias, float* __restrict__ C)
{
    __shared__ uint16_t lA[FBM * BK];
    __shared__ uint16_t lB[FBN * BK];
    const int t    = threadIdx.x;
    const int wave = t >> 6;
    const int lane = t & 63;
    const int bn = blockIdx.x, bm = blockIdx.y;
    const int wm = wave >> 1, wn = wave & 1;

    f32x4_t acc[4][4];
#pragma unroll
    for (int a = 0; a < 4; ++a)
#pragma unroll
        for (int b = 0; b < 4; ++b)
            acc[a][b] = (f32x4_t){0.f, 0.f, 0.f, 0.f};

    const int fr  = lane & 15;
    const int fkb = (lane >> 4) << 3;
    const uint16_t* pA[4];
    const uint16_t* pB[4];
#pragma unroll
    for (int i = 0; i < 4; ++i) {
        pA[i] = lA + (wm * 64 + i * 16 + fr) * BK + fkb;
        pB[i] = lB + (wn * 64 + i * 16 + fr) * BK + fkb;
    }

    const int mr = t >> 1;
    const int mc = (t & 1) << 4;
    int ng = bn * FBN + mr;
    int bcp = ng >> 10;
    int bo  = ng & 1023;

#pragma unroll 1
    for (int kb = 0; kb < K_DIM; kb += BK) {
        const float* pa = x + (size_t)(bm * FBM + mr) * K_DIM + kb + mc;
        float4 a0 = ((const float4*)pa)[0], a1 = ((const float4*)pa)[1],
               a2 = ((const float4*)pa)[2], a3 = ((const float4*)pa)[3];
        uint4 wv0 = make_uint4(pack2bf(a0.x, a0.y), pack2bf(a0.z, a0.w),
                               pack2bf(a1.x, a1.y), pack2bf(a1.z, a1.w));
        uint4 wv1 = make_uint4(pack2bf(a2.x, a2.y), pack2bf(a2.z, a2.w),
                               pack2bf(a3.x, a3.y), pack2bf(a3.z, a3.w));
        *(uint4*)(lA + mr * BK + mc)     = wv0;
        *(uint4*)(lA + mr * BK + mc + 8) = wv1;

        int k0 = kb + mc;
        int c  = k0 >> 10, ii = k0 & 1023;
        int tsel = bcp ^ c;
        const float* w = (tsel == 0) ? wrr : (tsel == 1) ? wri : (tsel == 2) ? wrj : wrk;
        float s = ((0x428Eu >> ((bcp << 2) | c)) & 1u) ? -1.0f : 1.0f;
        const float* pb = w + (size_t)bo * QO + ii;
        float4 b0 = ((const float4*)pb)[0], b1 = ((const float4*)pb)[1],
               b2 = ((const float4*)pb)[2], b3 = ((const float4*)pb)[3];
        uint4 u0 = make_uint4(pack2bf(s * b0.x, s * b0.y), pack2bf(s * b0.z, s * b0.w),
                              pack2bf(s * b1.x, s * b1.y), pack2bf(s * b1.z, s * b1.w));
        uint4 u1 = make_uint4(pack2bf(s * b2.x, s * b2.y), pack2bf(s * b2.z, s * b2.w),
                              pack2bf(s * b3.x, s * b3.y), pack2bf(s * b3.z, s * b3.w));
        *(uint4*)(lB + mr * BK + mc)     = u0;
        *(uint4*)(lB + mr * BK + mc + 8) = u1;
        __syncthreads();

        bf16x8_t af[4], bfr[4];
#pragma unroll
        for (int i = 0; i < 4; ++i) {
            af[i]  = *(const bf16x8_t*)pA[i];
            bfr[i] = *(const bf16x8_t*)pB[i];
        }
#pragma unroll
        for (int mi = 0; mi < 4; ++mi)
#pragma unroll
            for (int ni = 0; ni < 4; ++ni)
                acc[mi][ni] = __builtin_amdgcn_mfma_f32_16x16x32_bf16(
                    af[mi], bfr[ni], acc[mi][ni], 0, 0, 0);
        __syncthreads();
    }

    const int row0 = bm * FBM + wm * 64 + ((lane >> 4) << 2);
    const int col0 = bn * FBN + wn * 64 + (lane & 15);
#pragma unroll
    for (int ni = 0; ni < 4; ++ni) {
        const int col = col0 + ni * 16;
        const float bv = bias[col & (QO - 1)];
#pragma unroll
        for (int mi = 0; mi < 4; ++mi) {
            const int r = row0 + mi * 16;
            float* cptr = C + (size_t)r * N_DIM + col;
#pragma unroll
            for (int rr = 0; rr < 4; ++rr)
                cptr[(size_t)rr * N_DIM] = acc[mi][ni][rr] + bv;
        }
    }
}

extern "C" void kernel_launch(void* const* d_in, const int* in_sizes, int n_in,
                              void* d_out, int out_size, void* d_ws, size_t ws_size,
                              hipStream_t stream) {
    const float* x   = (const float*)d_in[0];
    const float* wrr = (const float*)d_in[1];
    const float* wri = (const float*)d_in[2];
    const float* wrj = (const float*)d_in[3];
    const float* wrk = (const float*)d_in[4];
    const float* brr = (const float*)d_in[5];
    float* out = (float*)d_out;

    const size_t xb_bytes = (size_t)M_DIM * K_DIM * 2;   // 64 MiB
    const size_t wb_bytes = (size_t)N_DIM * K_DIM * 2;   // 32 MiB

    if (ws_size >= xb_bytes + wb_bytes) {
        uint16_t* xb = (uint16_t*)d_ws;
        uint16_t* wb = (uint16_t*)((char*)d_ws + xb_bytes);
        const int nx8 = M_DIM * K_DIM / 8;
        cvt_x_kernel<<<nx8 / 256, 256, 0, stream>>>(x, xb, nx8);
        const int nw8 = N_DIM * K_DIM / 8;
        build_w_kernel<<<nw8 / 256, 256, 0, stream>>>(wrr, wri, wrj, wrk, wb, nw8);
        dim3 grid(N_DIM / BN, M_DIM / BM);
        qgemm256_kernel<<<grid, 256, 0, stream>>>(xb, wb, brr, out);
    } else {
        dim3 grid(N_DIM / FBN, M_DIM / FBM);
        qgemm_fb_kernel<<<grid, 256, 0, stream>>>(x, wrr, wri, wrj, wrk, brr, out);
    }
}